// Round 11
// baseline (529.238 us; speedup 1.0000x reference)
//
#include <hip/hip_runtime.h>
#include <hip/hip_bf16.h>
#include <math.h>
#include <stdint.h>

// Problem constants (deterministic from setup_inputs)
#define NB 32
#define NQ 300
#define ND 256
#define NH 8
#define HD 32
#define NL 4
#define NP 4
#define V_TOT 8500           // 6400+1600+400+100
#define BQ_TOT (NB*NQ)       // 9600
#define MVAL (NB*V_TOT)      // 272000
#define NOA 384              // fused off(256)+attn(128) cols

typedef short v8s __attribute__((ext_vector_type(8)));
typedef float v4f __attribute__((ext_vector_type(4)));

#define AS1 __attribute__((address_space(1)))
#define AS3 __attribute__((address_space(3)))

__device__ __forceinline__ void copy16_async(const void* g, void* l) {
#if __has_builtin(__builtin_amdgcn_global_load_lds)
    __builtin_amdgcn_global_load_lds((const AS1 unsigned int*)g,
                                     (AS3 unsigned int*)l, 16, 0, 0);
#else
    *(uint4*)l = *(const uint4*)g;
#endif
}

__device__ __forceinline__ unsigned short f2bf_rne(float x) {
    unsigned u = __float_as_uint(x);
    u += 0x7fffu + ((u >> 16) & 1u);
    return (unsigned short)(u >> 16);
}
__device__ __forceinline__ float bf2f(unsigned short b) {
    return __uint_as_float(((unsigned)b) << 16);
}

// RNE hi/lo split of an f32 pair into two packed-bf16 words using the
// packed convert (v_cvt_pk_bf16_f32). lo = x - hi is exact.
__device__ __forceinline__ void split2(float f0, float f1,
                                       unsigned& hp, unsigned& lp) {
    float2 v; v.x = f0; v.y = f1;
    __hip_bfloat162 h = __float22bfloat162_rn(v);
    unsigned hu; __builtin_memcpy(&hu, &h, 4);
    const float h0 = __uint_as_float(hu << 16);
    const float h1 = __uint_as_float(hu & 0xffff0000u);
    float2 l; l.x = f0 - h0; l.y = f1 - h1;
    __hip_bfloat162 lo = __float22bfloat162_rn(l);
    unsigned lu; __builtin_memcpy(&lu, &lo, 4);
    hp = hu; lp = lu;
}

// Swizzled flat position of element (n,k) in a prepped [N][256] bf16 array.
// Within each 32-k tile the 4 octets (8 els) are XOR-permuted by ((n>>1)&3)
// -> fragment reads spread across all 32 banks (0 conflicts, measured r3).
__device__ __forceinline__ int swz_pos(int n, int k) {
    const int base = k & ~31;
    const int o = (k >> 3) & 3;
    const int op = o ^ ((n >> 1) & 3);
    return n * 256 + base + (op << 3) + (k & 7);
}

// ---------------------------------------------------------------------------
// Prep: transpose + hi/lo-split (RNE) all three weight matrices into
// n-major swizzled bf16; concat biases for the fused off/attn projection.
// ---------------------------------------------------------------------------
__global__ __launch_bounds__(256) void prep_weights(
    const float* __restrict__ W_val, const float* __restrict__ W_off,
    const float* __restrict__ W_attn, const float* __restrict__ W_out,
    const float* __restrict__ b_off, const float* __restrict__ b_attn,
    unsigned short* __restrict__ Bval_h, unsigned short* __restrict__ Bval_l,
    unsigned short* __restrict__ Boa_h,  unsigned short* __restrict__ Boa_l,
    unsigned short* __restrict__ Bout_h, unsigned short* __restrict__ Bout_l,
    float* __restrict__ b_oa)
{
    const int t = blockIdx.x * 256 + threadIdx.x;
    if (t < 65536) {
        const int n = t >> 8, k = t & 255;
        const float x = W_val[k * 256 + n];
        const unsigned short hi = f2bf_rne(x);
        const unsigned short lo = f2bf_rne(x - bf2f(hi));
        const int p = swz_pos(n, k);
        Bval_h[p] = hi; Bval_l[p] = lo;
    } else if (t < 65536 + 98304) {
        const int t2 = t - 65536;
        const int n = t2 >> 8, k = t2 & 255;
        const float x = (n < 256) ? W_off[k * 256 + n] : W_attn[k * 128 + (n - 256)];
        const unsigned short hi = f2bf_rne(x);
        const unsigned short lo = f2bf_rne(x - bf2f(hi));
        const int p = swz_pos(n, k);
        Boa_h[p] = hi; Boa_l[p] = lo;
    } else if (t < 229376) {
        const int t3 = t - 163840;
        const int n = t3 >> 8, k = t3 & 255;
        const float x = W_out[k * 256 + n];
        const unsigned short hi = f2bf_rne(x);
        const unsigned short lo = f2bf_rne(x - bf2f(hi));
        const int p = swz_pos(n, k);
        Bout_h[p] = hi; Bout_l[p] = lo;
    } else {
        const int t4 = t - 229376;
        if (t4 < NOA) b_oa[t4] = (t4 < 256) ? b_off[t4] : b_attn[t4 - 256];
    }
}

// ---------------------------------------------------------------------------
// GEMM, f32 A: C = A(Mx256) @ B(256xN) + bias, bf16-split 3-product MFMA.
// r10 schedule (B LDS dbuf + counted vmcnt, proven) + MINIMAL-LDS-READ
// MFMA region: preload all 8 A fragments once (8 ds_read_b128), then
// j-outer loop loading each bh/bl exactly once -> 16 reads/step instead
// of the up-to-40 the per-(i,j) form could emit under the 84-VGPR cap.
// Per-acc accumulation order (hh,hl,lh) unchanged -> bit-identical.
// Sync schedule per step t (unchanged from r10):
//   barrier-1: lgkmcnt(0). | B(t+1) asyncs -> buf^1 (oldest VMEM) |
//   fence+sched_barrier | split A(t) (forces B(t) via <=vmcnt(4)) |
//   A(t+1) prefetch (youngest) | A ds_writes |
//   barrier-2: vmcnt(8) lgkmcnt(0) (only B(t+1)+A(t+1) outstanding);
//   vmcnt(0) at t=7.
// LDS 48 KB -> 3 blocks/CU.
// mode 0: Cf row-major [M][ldc] f32.
// mode 1: Cb = bf16 val layout C[((b*NH+h)*V_TOT+v)*HD+dh], row=(b,v), col=(h,dh)
// ---------------------------------------------------------------------------
__global__ __launch_bounds__(256, 3) void gemm_a32(
    const float* __restrict__ A,
    const unsigned short* __restrict__ Bh,
    const unsigned short* __restrict__ Bl,
    const float* __restrict__ bias,
    float* __restrict__ Cf,
    unsigned short* __restrict__ Cb,
    int ldc, int mode)
{
    __shared__ unsigned short Ah[128][32];        // octet-XOR swizzled
    __shared__ unsigned short Al[128][32];
    __shared__ unsigned short Bs[2][2][128][32];  // [buf][hi/lo], swizzled

    const int tid  = threadIdx.x;
    const int col0 = blockIdx.x * 128;            // N-tile (fast axis)
    const int row0 = blockIdx.y * 128;            // M-tile
    const int wave = tid >> 6;
    const int lane = tid & 63;
    const int wm   = (wave >> 1) * 64;
    const int wn   = (wave & 1) * 64;
    const int m16  = lane & 15;
    const int quad = lane >> 4;

    // ---- per-thread A-staging coords (2 quarter-rows of 8 f32) ----
    const int i0  = tid;
    const int i1  = tid + 256;
    const int r0_ = i0 >> 2, o0_ = i0 & 3;
    const int r1_ = i1 >> 2, o1_ = i1 & 3;
    const int oo0 = (o0_ ^ ((r0_ >> 1) & 3)) << 3;   // swizzled LDS elem offset
    const int oo1 = (o1_ ^ ((r1_ >> 1) & 3)) << 3;
    const float* Ap0 = A + (size_t)(row0 + r0_) * 256 + o0_ * 8;
    const float* Ap1 = A + (size_t)(row0 + r1_) * 256 + o1_ * 8;

    // ---- per-thread B-staging pointers (hoisted; step advance = 64 B imm) ----
    const int lin0 = (wave * 2 + 0) * 1024 + lane * 16;
    const int lin1 = (wave * 2 + 1) * 1024 + lane * 16;
    const char* pBh0 = (const char*)Bh + ((size_t)(col0 + (lin0 >> 6)) * 256) * 2 + (lin0 & 63);
    const char* pBl0 = (const char*)Bl + ((size_t)(col0 + (lin0 >> 6)) * 256) * 2 + (lin0 & 63);
    const char* pBh1 = (const char*)Bh + ((size_t)(col0 + (lin1 >> 6)) * 256) * 2 + (lin1 & 63);
    const char* pBl1 = (const char*)Bl + ((size_t)(col0 + (lin1 >> 6)) * 256) * 2 + (lin1 & 63);

    v4f acc[4][4] = {};

    // ---- prologue: B(0) asyncs -> buf0 (oldest), then A(0) -> regs ----
    copy16_async(pBh0, (char*)&Bs[0][0][0][0] + lin0);
    copy16_async(pBh1, (char*)&Bs[0][0][0][0] + lin1);
    copy16_async(pBl0, (char*)&Bs[0][1][0][0] + lin0);
    copy16_async(pBl1, (char*)&Bs[0][1][0][0] + lin1);
    asm volatile("" ::: "memory");
    __builtin_amdgcn_sched_barrier(0);
    float4 f00 = *(const float4*)(Ap0);
    float4 f01 = *(const float4*)(Ap0 + 4);
    float4 f10 = *(const float4*)(Ap1);
    float4 f11 = *(const float4*)(Ap1 + 4);

#pragma unroll
    for (int t = 0; t < 8; ++t) {
        const int buf = t & 1;                    // compile-time (full unroll)

        // ---- barrier-1 (raw): previous step's LDS readers done ----
        asm volatile("s_waitcnt lgkmcnt(0)" ::: "memory");
        __builtin_amdgcn_s_barrier();

        // ---- issue B(t+1) -> buf^1 (oldest VMEM of this step) ----
        if (t < 7) {
            const int nb = buf ^ 1;
            copy16_async(pBh0 + (t + 1) * 64, (char*)&Bs[nb][0][0][0] + lin0);
            copy16_async(pBh1 + (t + 1) * 64, (char*)&Bs[nb][0][0][0] + lin1);
            copy16_async(pBl0 + (t + 1) * 64, (char*)&Bs[nb][1][0][0] + lin0);
            copy16_async(pBl1 + (t + 1) * 64, (char*)&Bs[nb][1][0][0] + lin1);
        }

        // pin issue order: B(t+1) older than everything below
        asm volatile("" ::: "memory");
        __builtin_amdgcn_sched_barrier(0);

        // ---- split A(t): the implicit wait on A(t) regs (<= vmcnt(4))
        //      also forces B(t), both with ~a full step of cover ----
        unsigned hpk0[4], lpk0[4], hpk1[4], lpk1[4];
        split2(f00.x, f00.y, hpk0[0], lpk0[0]);
        split2(f00.z, f00.w, hpk0[1], lpk0[1]);
        split2(f01.x, f01.y, hpk0[2], lpk0[2]);
        split2(f01.z, f01.w, hpk0[3], lpk0[3]);
        split2(f10.x, f10.y, hpk1[0], lpk1[0]);
        split2(f10.z, f10.w, hpk1[1], lpk1[1]);
        split2(f11.x, f11.y, hpk1[2], lpk1[2]);
        split2(f11.z, f11.w, hpk1[3], lpk1[3]);

        // ---- prefetch A(t+1) into the just-freed regs (youngest VMEM) ----
        if (t < 7) {
            const int k1 = (t + 1) * 32;
            f00 = *(const float4*)(Ap0 + k1);
            f01 = *(const float4*)(Ap0 + k1 + 4);
            f10 = *(const float4*)(Ap1 + k1);
            f11 = *(const float4*)(Ap1 + k1 + 4);
        }

        // ---- A packed hi/lo -> LDS (b128, swizzled octet) ----
        *(uint4*)&Ah[r0_][oo0] = make_uint4(hpk0[0], hpk0[1], hpk0[2], hpk0[3]);
        *(uint4*)&Al[r0_][oo0] = make_uint4(lpk0[0], lpk0[1], lpk0[2], lpk0[3]);
        *(uint4*)&Ah[r1_][oo1] = make_uint4(hpk1[0], hpk1[1], hpk1[2], hpk1[3]);
        *(uint4*)&Al[r1_][oo1] = make_uint4(lpk1[0], lpk1[1], lpk1[2], lpk1[3]);

        // ---- barrier-2 (raw, counted): only next-step VMEM outstanding
        //      (B(t+1)x4 + A(t+1)x4 = 8); lgkm flushes A ds_writes ----
        if (t < 7) {
            asm volatile("s_waitcnt vmcnt(8) lgkmcnt(0)" ::: "memory");
        } else {
            asm volatile("s_waitcnt vmcnt(0) lgkmcnt(0)" ::: "memory");
        }
        __builtin_amdgcn_s_barrier();

        // ---- MFMA region, minimal LDS reads: preload all 8 A-frags
        //      (8 ds_read_b128), then each bh/bl read exactly once ----
        v8s ahf[4], alf[4];
#pragma unroll
        for (int i = 0; i < 4; ++i) {
            const int r  = wm + i * 16 + m16;
            const int ka = (quad ^ ((r >> 1) & 3)) << 3;
            ahf[i] = *(v8s*)&Ah[r][ka];
            alf[i] = *(v8s*)&Al[r][ka];
        }
#pragma unroll
        for (int j = 0; j < 4; ++j) {
            const int n  = wn + j * 16 + m16;
            const int ko = (quad ^ ((n >> 1) & 3)) << 3;
            const v8s bh = *(v8s*)&Bs[buf][0][n][ko];
            const v8s bl = *(v8s*)&Bs[buf][1][n][ko];
#pragma unroll
            for (int i = 0; i < 4; ++i) {
                acc[i][j] = __builtin_amdgcn_mfma_f32_16x16x32_bf16(ahf[i], bh, acc[i][j], 0, 0, 0);
                acc[i][j] = __builtin_amdgcn_mfma_f32_16x16x32_bf16(ahf[i], bl, acc[i][j], 0, 0, 0);
                acc[i][j] = __builtin_amdgcn_mfma_f32_16x16x32_bf16(alf[i], bh, acc[i][j], 0, 0, 0);
            }
        }
    }

    // ---- epilogue: D[row=quad*4+reg][col=lane&15] ----
#pragma unroll
    for (int j = 0; j < 4; ++j) {
        const int cl = col0 + wn + j * 16 + m16;
        const float bb = bias[cl];
        if (mode == 0) {
#pragma unroll
            for (int i = 0; i < 4; ++i)
#pragma unroll
                for (int r = 0; r < 4; ++r) {
                    const int R = row0 + wm + i * 16 + quad * 4 + r;
                    Cf[(size_t)R * ldc + cl] = acc[i][j][r] + bb;
                }
        } else {
            const int h  = cl >> 5;
            const int dh = cl & 31;
#pragma unroll
            for (int i = 0; i < 4; ++i)
#pragma unroll
                for (int r = 0; r < 4; ++r) {
                    const int R = row0 + wm + i * 16 + quad * 4 + r;
                    const unsigned b = (unsigned)R / V_TOT;
                    const int v = R - (int)b * V_TOT;
                    Cb[(((size_t)(b * NH + h)) * V_TOT + v) * HD + dh] =
                        f2bf_rne(acc[i][j][r] + bb);
                }
        }
    }
}

// ---------------------------------------------------------------------------
// GEMM, bf16 A (pre-swizzled rows): C = A(Mx256) @ B(256xN) + bias, f32 out.
// 2-product (A * (Bhi+Blo)). All operands async-staged, 2-phase pipelined,
// one barrier per K-step.
// ---------------------------------------------------------------------------
__global__ __launch_bounds__(256) void gemm_a16(
    const unsigned short* __restrict__ A,     // [M][256] bf16, swizzled octets
    const unsigned short* __restrict__ Bh,
    const unsigned short* __restrict__ Bl,
    const float* __restrict__ bias,
    float* __restrict__ C, int ldc)
{
    __shared__ unsigned short As[2][128][32];
    __shared__ unsigned short Bs[2][2][128][32];

    const int tid  = threadIdx.x;
    const int row0 = blockIdx.x * 128;
    const int col0 = blockIdx.y * 128;
    const int wave = tid >> 6;
    const int lane = tid & 63;
    const int wm   = (wave >> 1) * 64;
    const int wn   = (wave & 1) * 64;
    const int m16  = lane & 15;
    const int quad = lane >> 4;

    v4f acc[4][4] = {};

    // prologue: stage K-step 0 into buffer 0
#pragma unroll
    for (int c = 0; c < 2; ++c) {
        const int linear = (wave * 2 + c) * 1024 + lane * 16;
        const int n   = linear >> 6;
        const int off = linear & 63;
        copy16_async((const char*)A  + ((size_t)(row0 + n) * 256 + 0) * 2 + off,
                     (char*)&As[0][0][0] + linear);
        copy16_async((const char*)Bh + ((size_t)(col0 + n) * 256 + 0) * 2 + off,
                     (char*)&Bs[0][0][0][0] + linear);
        copy16_async((const char*)Bl + ((size_t)(col0 + n) * 256 + 0) * 2 + off,
                     (char*)&Bs[0][1][0][0] + linear);
    }
    __syncthreads();

    for (int t = 0; t < 8; ++t) {
        const int buf = t & 1;
        const int nb  = buf ^ 1;
        const int k1  = (t + 1) << 5;

        if (t < 7) {
#pragma unroll
            for (int c = 0; c < 2; ++c) {
                const int linear = (wave * 2 + c) * 1024 + lane * 16;
                const int n   = linear >> 6;
                const int off = linear & 63;
                copy16_async((const char*)A  + ((size_t)(row0 + n) * 256 + k1) * 2 + off,
                             (char*)&As[nb][0][0] + linear);
                copy16_async((const char*)Bh + ((size_t)(col0 + n) * 256 + k1) * 2 + off,
                             (char*)&Bs[nb][0][0][0] + linear);
                copy16_async((const char*)Bl + ((size_t)(col0 + n) * 256 + k1) * 2 + off,
                             (char*)&Bs[nb][1][0][0] + linear);
            }
        }

        v8s a[4], bh[4], bl[4];
#pragma unroll
        for (int i = 0; i < 4; ++i) {
            const int r  = wm + i * 16 + m16;
            const int ka = (quad ^ ((r >> 1) & 3)) << 3;
            a[i] = *(v8s*)&As[buf][r][ka];
            const int n  = wn + i * 16 + m16;
            const int kb = (quad ^ ((n >> 1) & 3)) << 3;
            bh[i] = *(v8s*)&Bs[buf][0][n][kb];
            bl[i] = *(v8s*)&Bs[buf][1][n][kb];
        }
#pragma unroll
        for (int i = 0; i < 4; ++i)
#pragma unroll
            for (int j = 0; j < 4; ++j) {
                acc[i][j] = __builtin_amdgcn_mfma_f32_16x16x32_bf16(a[i], bh[j], acc[i][j], 0, 0, 0);
                acc[i][j] = __builtin_amdgcn_mfma_f32_16x16x32_bf16(a[i], bl[j], acc[i][j], 0, 0, 0);
            }

        __syncthreads();
    }

#pragma unroll
    for (int j = 0; j < 4; ++j) {
        const int cl = col0 + wn + j * 16 + m16;
        const float bb = bias[cl];
#pragma unroll
        for (int i = 0; i < 4; ++i)
#pragma unroll
            for (int r = 0; r < 4; ++r) {
                const int R = row0 + wm + i * 16 + quad * 4 + r;
                C[(size_t)R * ldc + cl] = acc[i][j][r] + bb;
            }
    }
}

// ---------------------------------------------------------------------------
// Sampler v2.1: softmax(16) + bilinear gather + weighted sum.
//  * POINT-SPLIT x2 TLP: thread = (bq, half, h, d8); partial sums combined
//    with one __shfl_xor(acc,32) (half = lane bit 5).
//  * XCD-CHUNK SWIZZLE: swz=(g&7)*300+g/8 (bijective) for val L2 locality.
//  * attn logits loaded as 4x float4 (explicit vectorization).
//  * Rule #20: aw[] accessed via half-ternary with compile-time indices.
// ---------------------------------------------------------------------------
__global__ __launch_bounds__(256) void sample_kernel(
    const float* __restrict__ refp,
    const float* __restrict__ offattn,            // [9600][384]
    const unsigned short* __restrict__ val,       // [b][h][V][32] bf16
    unsigned short* __restrict__ pre)             // [9600][256] bf16 swizzled
{
    const int g  = blockIdx.x;                      // 0..2399
    const int sb = (g & 7) * 300 + (g >> 3);        // XCD-chunk swizzle
    const int t  = sb * 256 + threadIdx.x;          // 0 .. 614399
    const int d8   = t & 3;
    const int h    = (t >> 2) & 7;
    const int half = (t >> 5) & 1;                  // lane bit 5
    const int bq   = t >> 6;
    const int b    = bq / NQ;

    const float* rp = refp + (size_t)bq * 8;
    const float* op = offattn + (size_t)bq * 384 + h * 32;
    const float* ap = offattn + (size_t)bq * 384 + 256 + h * 16;

    // softmax over the 16 (l,p) logits (vector loads; all threads)
    float aw[16];
    {
        const float4 v0 = *(const float4*)(ap);
        const float4 v1 = *(const float4*)(ap + 4);
        const float4 v2 = *(const float4*)(ap + 8);
        const float4 v3 = *(const float4*)(ap + 12);
        aw[0]=v0.x; aw[1]=v0.y; aw[2]=v0.z; aw[3]=v0.w;
        aw[4]=v1.x; aw[5]=v1.y; aw[6]=v1.z; aw[7]=v1.w;
        aw[8]=v2.x; aw[9]=v2.y; aw[10]=v2.z; aw[11]=v2.w;
        aw[12]=v3.x; aw[13]=v3.y; aw[14]=v3.z; aw[15]=v3.w;
    }
    float m = -1e30f;
#pragma unroll
    for (int i = 0; i < 16; ++i) m = fmaxf(m, aw[i]);
    float s = 0.f;
#pragma unroll
    for (int i = 0; i < 16; ++i) { aw[i] = __expf(aw[i] - m); s += aw[i]; }
    const float inv = 1.f / s;
#pragma unroll
    for (int i = 0; i < 16; ++i) aw[i] *= inv;

    float acc[8] = {};
#pragma unroll
    for (int li = 0; li < 2; ++li) {
        // l = half*2 + li; all level-dependent constants via half-ternary
        const int Wl = li ? (half ? 10 : 40) : (half ? 20 : 80);
        const int St = li ? (half ? 8400 : 6400) : (half ? 8000 : 0);
        const int l2 = (half ? 2 : 0) + li;          // for global-ptr offsets
        const float fW = (float)Wl, fH = (float)Wl;
        const float rx = rp[l2 * 2 + 0];
        const float ry = rp[l2 * 2 + 1];
        const unsigned short* vb =
            val + (((size_t)(b * NH + h)) * V_TOT + St) * HD + d8 * 8;
#pragma unroll
        for (int p = 0; p < NP; ++p) {
            const float ox = op[l2 * 8 + p * 2 + 0];
            const float oy = op[l2 * 8 + p * 2 + 1];
            const float w  = half ? aw[8 + li * 4 + p] : aw[li * 4 + p];
            const float x = fmaf(rx, fW, ox) - 0.5f;
            const float y = fmaf(ry, fH, oy) - 0.5f;
            const float x0f = floorf(x), y0f = floorf(y);
            const int   x0 = (int)x0f,  y0 = (int)y0f;
            const float wx1 = x - x0f,  wy1 = y - y0f;
            const float wx0 = 1.f - wx1, wy0 = 1.f - wy1;
#pragma unroll
            for (int cy = 0; cy < 2; ++cy) {
#pragma unroll
                for (int cx = 0; cx < 2; ++cx) {
                    const int xi = x0 + cx;
                    const int yi = y0 + cy;
                    float cw = (cx ? wx1 : wx0) * (cy ? wy1 : wy0) * w;
                    const bool valid = (xi >= 0) && (xi < Wl) && (yi >= 0) && (yi < Wl);
                    cw = valid ? cw : 0.f;
                    const int xc = xi < 0 ? 0 : (xi > Wl - 1 ? Wl - 1 : xi);
                    const int yc = yi < 0 ? 0 : (yi > Wl - 1 ? Wl - 1 : yi);
                    const uint4 gld = *(const uint4*)(vb + (size_t)(yc * Wl + xc) * HD);
                    const unsigned gu[4] = {gld.x, gld.y, gld.z, gld.w};
#pragma unroll
                    for (int e = 0; e < 4; ++e) {
                        acc[2*e]   = fmaf(cw, __uint_as_float(gu[e] << 16),        acc[2*e]);
                        acc[2*e+1] = fmaf(cw, __uint_as_float(gu[e] & 0xffff0000u), acc[2*e+1]);
                    }
                }
            }
        }
    }

    // combine the two level-halves (partner lane = lane ^ 32)
#pragma unroll
    for (int e = 0; e < 8; ++e) acc[e] += __shfl_xor(acc[e], 32);

    if (half == 0) {
        unsigned o[4];
#pragma unroll
        for (int e = 0; e < 4; ++e)
            o[e] = (unsigned)f2bf_rne(acc[2*e]) | ((unsigned)f2bf_rne(acc[2*e+1]) << 16);
        const int octswz = d8 ^ ((bq >> 1) & 3);
        *(uint4*)(pre + (size_t)bq * 256 + h * 32 + octswz * 8) =
            make_uint4(o[0], o[1], o[2], o[3]);
    }
}

// ---------------------------------------------------------------------------
extern "C" void kernel_launch(void* const* d_in, const int* in_sizes, int n_in,
                              void* d_out, int out_size, void* d_ws, size_t ws_size,
                              hipStream_t stream)
{
    const float* query  = (const float*)d_in[0];
    const float* refp   = (const float*)d_in[1];
    const float* value  = (const float*)d_in[2];
    const float* W_off  = (const float*)d_in[5];
    const float* b_off  = (const float*)d_in[6];
    const float* W_attn = (const float*)d_in[7];
    const float* b_attn = (const float*)d_in[8];
    const float* W_val  = (const float*)d_in[9];
    const float* b_val  = (const float*)d_in[10];
    const float* W_out  = (const float*)d_in[11];
    const float* b_out  = (const float*)d_in[12];
    float* out = (float*)d_out;

    char* ws = (char*)d_ws;
    unsigned short* val     = (unsigned short*)ws;                       // 139,264,000 B
    float*          offattn = (float*)(ws + 139264000);                  // 14,745,600 B
    unsigned short* pre     = (unsigned short*)(ws + 154009600);         //  4,915,200 B
    unsigned short* Bval_h  = (unsigned short*)(ws + 158924800);         //    131,072 B
    unsigned short* Bval_l  = Bval_h + 65536;
    unsigned short* Boa_h   = Bval_l + 65536;                            //    196,608 B
    unsigned short* Boa_l   = Boa_h + 98304;
    unsigned short* Bout_h  = Boa_l + 98304;
    unsigned short* Bout_l  = Bout_h + 65536;
    float*          b_oa    = (float*)(Bout_l + 65536);

    const dim3 blk(256);

    // 0) weight prep: transpose + RNE hi/lo split + swizzle + bias concat
    prep_weights<<<dim3(898), blk, 0, stream>>>(
        W_val, W_off, W_attn, W_out, b_off, b_attn,
        Bval_h, Bval_l, Boa_h, Boa_l, Bout_h, Bout_l, b_oa);

    // 1) val = value @ W_val + b_val -> bf16 [b][h][V][hd]   (grid: x=Ntile)
    gemm_a32<<<dim3(2, MVAL / 128), blk, 0, stream>>>(
        value, Bval_h, Bval_l, b_val, nullptr, val, 0, 1);

    // 2) fused off+attn projection -> f32 [9600][384]
    gemm_a32<<<dim3(3, BQ_TOT / 128), blk, 0, stream>>>(
        query, Boa_h, Boa_l, b_oa, offattn, nullptr, NOA, 0);

    // 3) softmax + bilinear sampling + weighted sum -> pre bf16 (swizzled)
    //    2x point-split TLP + XCD-chunk swizzle
    sample_kernel<<<dim3((BQ_TOT * 64) / 256), blk, 0, stream>>>(
        refp, offattn, val, pre);

    // 4) out = pre @ W_out + b_out -> f32 [9600][256]
    gemm_a16<<<dim3(BQ_TOT / 128, 2), blk, 0, stream>>>(
        pre, Bout_h, Bout_l, b_out, out, 256);
}